// Round 3
// baseline (3154.756 us; speedup 1.0000x reference)
//
#include <hip/hip_runtime.h>

#define HID 1024
#define NROW 8192
#define NCAT 16384   // [speech; text] concatenated rows

typedef unsigned short u16;
typedef short s16x8 __attribute__((ext_vector_type(8)));
typedef float f32x4 __attribute__((ext_vector_type(4)));

// ---- fp32 ~= bf16(hi) + bf16(lo), both round-to-nearest-even ----
// |x - hi| <= 2^-9|x|  ->  dropped lo*lo term ~2^-18, lo rounding ~2^-18.
__device__ __forceinline__ u16 rtn16(float x) {
  unsigned xb = __builtin_bit_cast(unsigned, x);
  return (u16)((xb + 0x7fffu + ((xb >> 16) & 1u)) >> 16);
}
__device__ __forceinline__ float fromh(u16 h) {
  return __builtin_bit_cast(float, (unsigned)h << 16);
}
__device__ __forceinline__ void split2(float x, u16 &h, u16 &l) {
  h = rtn16(x);
  l = rtn16(x - fromh(h));
}

// async global->LDS, 16B/lane; LDS dest must be wave-uniform base + lane*16
__device__ __forceinline__ void gl16(const void* g, void* l) {
  __builtin_amdgcn_global_load_lds(
      (const __attribute__((address_space(1))) unsigned int*)g,
      (__attribute__((address_space(3))) unsigned int*)l, 16, 0, 0);
}

// =====================================================================
// C[M,N] = A[M,K] @ Bt[N,K]^T (+bias[n]), fp32 emulated by split-bf16 MFMA:
//   C = Ah Bh + Ah Bl + Al Bh      (Al Bl ~2^-18 rel, dropped)
// AMODE 0: A pre-split (Agh/Agl) -> staged via global_load_lds (m97 path).
// AMODE 1: A fp32 (Agf) -> split in-kernel during staging (PV fallback).
// OUT_SPLIT: emit hi/lo bf16 planes (tensor is consumed by a later GEMM).
// WRITE_T:   emit transposed [N][M] split planes (produces vT for PV).
// Structure: 128x128 tile, BK=32, 2 barriers/K-step, 48 MFMA/K-step.
// =====================================================================
template<int AMODE, bool ADD_BIAS, bool WRITE_T, bool OUT_SPLIT>
__global__ void __launch_bounds__(256, 2)
gemm_bt(const u16* __restrict__ Agh, const u16* __restrict__ Agl,
        const float* __restrict__ Agf, int lda,
        const u16* __restrict__ Bgh, const u16* __restrict__ Bgl, int ldb,
        const float* __restrict__ bias,
        float* __restrict__ Cf, u16* __restrict__ Ch, u16* __restrict__ Cl,
        int ldc, int K, int tiles_n)
{
  __shared__ __align__(16) u16 sAh[128 * 32];
  __shared__ __align__(16) u16 sAl[128 * 32];
  __shared__ __align__(16) u16 sBh[128 * 32];
  __shared__ __align__(16) u16 sBl[128 * 32];

  const int tid = threadIdx.x;
  // bijective XCD-chunked swizzle (every grid here is a multiple of 8)
  const unsigned nwg = gridDim.x;
  const unsigned bid = blockIdx.x;
  const unsigned swz = (bid & 7u) * (nwg >> 3) + (bid >> 3);
  const int bm = (int)(swz / (unsigned)tiles_n) * 128;
  const int bn = (int)(swz % (unsigned)tiles_n) * 128;

  const int wave = tid >> 6;
  const int lane = tid & 63;
  const int wr = (wave >> 1) * 64;   // wave's 64x64 quadrant
  const int wc = (wave & 1) * 64;
  const int fr = lane & 15;          // fragment row (A) / col (B)
  const int fq = lane >> 4;          // k-chunk of 8

  // staging: chunk c covers tile-row c>>2, k-cols (c&3)*8..+8;
  // LDS byte offset c*16 == row*64 + kc*2 (linear, as gload_lds requires)
  const u16* pAh[2]; const u16* pAl[2];
  const u16* pBh[2]; const u16* pBl[2];
  u16* dA[2]; u16* dB[2];
  #pragma unroll
  for (int j = 0; j < 2; ++j) {
    int c = tid + j * 256;
    int row = c >> 2;
    int kc = (c & 3) * 8;
    if constexpr (AMODE == 0) {
      pAh[j] = Agh + (size_t)(bm + row) * lda + kc;
      pAl[j] = Agl + (size_t)(bm + row) * lda + kc;
    }
    pBh[j] = Bgh + (size_t)(bn + row) * ldb + kc;
    pBl[j] = Bgl + (size_t)(bn + row) * ldb + kc;
    dA[j] = (u16*)((char*)sAh + (size_t)c * 16);
    dB[j] = (u16*)((char*)sBh + (size_t)c * 16);
  }
  const size_t loOffA = (char*)sAl - (char*)sAh;
  const size_t loOffB = (char*)sBl - (char*)sBh;

  f32x4 acc[4][4] = {};

  for (int k0 = 0; k0 < K; k0 += 32) {
    if constexpr (AMODE == 0) {
      #pragma unroll
      for (int j = 0; j < 2; ++j) {
        gl16(pAh[j] + k0, dA[j]);
        gl16(pAl[j] + k0, (char*)dA[j] + loOffA);
        gl16(pBh[j] + k0, dB[j]);
        gl16(pBl[j] + k0, (char*)dB[j] + loOffB);
      }
    } else {
      #pragma unroll
      for (int j = 0; j < 2; ++j) {
        gl16(pBh[j] + k0, dB[j]);
        gl16(pBl[j] + k0, (char*)dB[j] + loOffB);
      }
      // A: fp32 load + split + ds_write (each thread: 16 floats of one row)
      const int row = tid >> 1;
      const int c0 = (tid & 1) * 16;
      const float4* src = (const float4*)(Agf + (size_t)(bm + row) * lda + k0 + c0);
      u16* dh = &sAh[row * 32 + c0];
      u16* dl = &sAl[row * 32 + c0];
      #pragma unroll
      for (int q = 0; q < 4; ++q) {
        float4 v = src[q];
        ushort4 h4, l4;
        split2(v.x, h4.x, l4.x); split2(v.y, h4.y, l4.y);
        split2(v.z, h4.z, l4.z); split2(v.w, h4.w, l4.w);
        ((ushort4*)dh)[q] = h4;
        ((ushort4*)dl)[q] = l4;
      }
    }
    __syncthreads();

    s16x8 ah[4], al[4], bh[4], bl[4];
    #pragma unroll
    for (int m = 0; m < 4; ++m) {
      int r = (wr + m * 16 + fr) * 32 + fq * 8;
      ah[m] = *(const s16x8*)&sAh[r];
      al[m] = *(const s16x8*)&sAl[r];
    }
    #pragma unroll
    for (int n = 0; n < 4; ++n) {
      int r = (wc + n * 16 + fr) * 32 + fq * 8;
      bh[n] = *(const s16x8*)&sBh[r];
      bl[n] = *(const s16x8*)&sBl[r];
    }
    #pragma unroll
    for (int m = 0; m < 4; ++m)
      #pragma unroll
      for (int n = 0; n < 4; ++n) {
        acc[m][n] = __builtin_amdgcn_mfma_f32_16x16x32_bf16(ah[m], bh[n], acc[m][n], 0, 0, 0);
        acc[m][n] = __builtin_amdgcn_mfma_f32_16x16x32_bf16(ah[m], bl[n], acc[m][n], 0, 0, 0);
        acc[m][n] = __builtin_amdgcn_mfma_f32_16x16x32_bf16(al[m], bh[n], acc[m][n], 0, 0, 0);
      }
    __syncthreads();
  }

  // epilogue — C/D frag: col = fr, row = fq*4 + i   [m89-verified layout]
  #pragma unroll
  for (int m = 0; m < 4; ++m) {
    int row0 = bm + wr + m * 16 + fq * 4;
    #pragma unroll
    for (int n = 0; n < 4; ++n) {
      int col = bn + wc + n * 16 + fr;
      f32x4 v = acc[m][n];
      if (ADD_BIAS) v = v + bias[col];
      if constexpr (WRITE_T) {            // split planes, [N][M]
        ushort4 h4, l4;
        split2(v[0], h4.x, l4.x); split2(v[1], h4.y, l4.y);
        split2(v[2], h4.z, l4.z); split2(v[3], h4.w, l4.w);
        *(ushort4*)&Ch[(size_t)col * ldc + row0] = h4;
        *(ushort4*)&Cl[(size_t)col * ldc + row0] = l4;
      } else if constexpr (OUT_SPLIT) {   // split planes, [M][N]
        #pragma unroll
        for (int i = 0; i < 4; ++i) {
          u16 h, l; split2(v[i], h, l);
          Ch[(size_t)(row0 + i) * ldc + col] = h;
          Cl[(size_t)(row0 + i) * ldc + col] = l;
        }
      } else {                            // fp32, [M][N]
        #pragma unroll
        for (int i = 0; i < 4; ++i)
          Cf[(size_t)(row0 + i) * ldc + col] = v[i];
      }
    }
  }
}

// =====================================================================
// in-place row softmax (rows of 8192); optionally emit hi/lo split planes
// =====================================================================
template<bool SPLIT>
__global__ void __launch_bounds__(256)
softmax_rows(float* __restrict__ S, ushort4* __restrict__ Wh, ushort4* __restrict__ Wl)
{
  __shared__ float redm[4];
  __shared__ float reds[4];
  const int tid = threadIdx.x;
  float* p = S + (size_t)blockIdx.x * NROW;

  float4 v[8];
  float mx = -3.4e38f;
  #pragma unroll
  for (int i = 0; i < 8; ++i) {
    v[i] = *(const float4*)(p + ((tid + i * 256) << 2));
    mx = fmaxf(mx, fmaxf(fmaxf(v[i].x, v[i].y), fmaxf(v[i].z, v[i].w)));
  }
  #pragma unroll
  for (int off = 32; off > 0; off >>= 1)
    mx = fmaxf(mx, __shfl_xor(mx, off));
  if ((tid & 63) == 0) redm[tid >> 6] = mx;
  __syncthreads();
  mx = fmaxf(fmaxf(redm[0], redm[1]), fmaxf(redm[2], redm[3]));

  const float c = 1.44269504088896340736f;
  float s = 0.0f;
  #pragma unroll
  for (int i = 0; i < 8; ++i) {
    v[i].x = exp2f((v[i].x - mx) * c);
    v[i].y = exp2f((v[i].y - mx) * c);
    v[i].z = exp2f((v[i].z - mx) * c);
    v[i].w = exp2f((v[i].w - mx) * c);
    s += v[i].x + v[i].y + v[i].z + v[i].w;
  }
  #pragma unroll
  for (int off = 32; off > 0; off >>= 1)
    s += __shfl_xor(s, off);
  if ((tid & 63) == 0) reds[tid >> 6] = s;
  __syncthreads();
  s = reds[0] + reds[1] + reds[2] + reds[3];
  const float inv = 1.0f / s;
  const size_t rb4 = (size_t)blockIdx.x * (NROW / 4);

  #pragma unroll
  for (int i = 0; i < 8; ++i) {
    float4 w4;
    w4.x = v[i].x * inv; w4.y = v[i].y * inv;
    w4.z = v[i].z * inv; w4.w = v[i].w * inv;
    *(float4*)(p + ((tid + i * 256) << 2)) = w4;
    if constexpr (SPLIT) {
      ushort4 h4, l4;
      split2(w4.x, h4.x, l4.x); split2(w4.y, h4.y, l4.y);
      split2(w4.z, h4.z, l4.z); split2(w4.w, h4.w, l4.w);
      size_t o = rb4 + tid + i * 256;
      Wh[o] = h4;
      Wl[o] = l4;
    }
  }
}

// conv1d(k=1, stride=4): out[r,c] = in[r, 4c] * w, emitted pre-split.
// flat: out[j] = in_flat[4j]*w -> float4 index j, component .x (coalesced).
__global__ void __launch_bounds__(256)
conv_split(const float4* __restrict__ in, const float* __restrict__ wp,
           ushort4* __restrict__ oh, ushort4* __restrict__ ol)
{
  const int i = blockIdx.x * 256 + threadIdx.x;   // over NH/4
  const float w = wp[0];
  float a = in[i * 4 + 0].x * w, b = in[i * 4 + 1].x * w;
  float c = in[i * 4 + 2].x * w, d = in[i * 4 + 3].x * w;
  ushort4 h4, l4;
  split2(a, h4.x, l4.x); split2(b, h4.y, l4.y);
  split2(c, h4.z, l4.z); split2(d, h4.w, l4.w);
  oh[i] = h4;
  ol[i] = l4;
}

// fp32 tensor -> hi/lo bf16 planes
__global__ void __launch_bounds__(256)
split_mat(const float4* __restrict__ in, ushort4* __restrict__ oh, ushort4* __restrict__ ol)
{
  const int i = blockIdx.x * 256 + threadIdx.x;
  float4 v = in[i];
  ushort4 h4, l4;
  split2(v.x, h4.x, l4.x); split2(v.y, h4.y, l4.y);
  split2(v.z, h4.z, l4.z); split2(v.w, h4.w, l4.w);
  oh[i] = h4;
  ol[i] = l4;
}

// 1024x1024 transpose + split (W stored [in][out]; GEMM wants Bt=[out][in])
__global__ void __launch_bounds__(256)
transpose_split(const float* __restrict__ in, u16* __restrict__ oh, u16* __restrict__ ol)
{
  __shared__ float t[32][33];
  const int tx = threadIdx.x & 31, ty = threadIdx.x >> 5;
  const int bx = blockIdx.x * 32, by = blockIdx.y * 32;
  #pragma unroll
  for (int i = 0; i < 32; i += 8)
    t[ty + i][tx] = in[(size_t)(by + ty + i) * HID + bx + tx];
  __syncthreads();
  #pragma unroll
  for (int i = 0; i < 32; i += 8) {
    float v = t[tx][ty + i];
    size_t o = (size_t)(bx + ty + i) * HID + by + tx;
    u16 h, l; split2(v, h, l);
    oh[o] = h;
    ol[o] = l;
  }
}

extern "C" void kernel_launch(void* const* d_in, const int* in_sizes, int n_in,
                              void* d_out, int out_size, void* d_ws, size_t ws_size,
                              hipStream_t stream)
{
  (void)in_sizes; (void)n_in; (void)out_size;
  const float* speech_embed = (const float*)d_in[0];
  const float* text  = (const float*)d_in[1];
  const float* convw = (const float*)d_in[2];
  const float* Wq = (const float*)d_in[3];
  const float* bq = (const float*)d_in[4];
  const float* Wk = (const float*)d_in[5];
  const float* bk = (const float*)d_in[6];
  const float* Wv = (const float*)d_in[7];
  const float* bv = (const float*)d_in[8];
  const float* Wo = (const float*)d_in[9];
  const float* bo = (const float*)d_in[10];
  float* out = (float*)d_out;

  const size_t NH = (size_t)NROW * HID;    // 8.39M
  const size_t NN = (size_t)NROW * NROW;   // 67.1M
  const size_t HH = (size_t)HID * HID;     // 1.05M

  // ---- workspace: bf16 split planes (u16 units) ----
  u16* base = (u16*)d_ws;
  size_t off = 0;
  auto alloc = [&](size_t n) { u16* p = base + off; off += n; return p; };
  // cat = [speech(0..8191); text(8192..16383)], contiguous for merged proj
  u16 *cath = alloc(2 * NH), *catl = alloc(2 * NH);
  u16 *sph = cath,       *spl = catl;
  u16 *txh = cath + NH,  *txl = catl + NH;
  u16 *wqh = alloc(HH), *wql = alloc(HH);
  u16 *wkh = alloc(HH), *wkl = alloc(HH);
  u16 *wvh = alloc(HH), *wvl = alloc(HH);
  u16 *woh = alloc(HH), *wol = alloc(HH);
  u16 *qh = alloc(2 * NH), *ql = alloc(2 * NH);   // [NCAT][HID]: stt | tts
  u16 *kh = alloc(2 * NH), *kl = alloc(2 * NH);   // [NCAT][HID]: tts | stt
  u16 *vth = alloc(2 * NH), *vtl = alloc(2 * NH); // [HID][NCAT]: tts | stt cols
  u16 *c1h = qh,      *c1l = ql;                  // ctx reuses dead q planes
  u16 *c2h = qh + NH, *c2l = ql + NH;
  // Path A: shared weights-split buffer (tts then stt, serialized)
  const bool pathA = ((off + 2 * NN) * sizeof(u16)) <= ws_size;
  u16 *wsh = nullptr, *wsl = nullptr;
  if (pathA) { wsh = alloc(NN); wsl = alloc(NN); }

  // ---- output layout (reference return order) ----
  float* tts_out = out;
  float* tts_w   = out + NH;
  float* stt_out = tts_w + NN;
  float* stt_w   = stt_out + NH;

  const dim3 blk(256);

  conv_split<<<NH / 1024, blk, 0, stream>>>((const float4*)speech_embed, convw,
                                            (ushort4*)sph, (ushort4*)spl);
  split_mat<<<NH / 1024, blk, 0, stream>>>((const float4*)text, (ushort4*)txh, (ushort4*)txl);
  const dim3 tg(32, 32);
  transpose_split<<<tg, blk, 0, stream>>>(Wq, wqh, wql);
  transpose_split<<<tg, blk, 0, stream>>>(Wk, wkh, wkl);
  transpose_split<<<tg, blk, 0, stream>>>(Wv, wvh, wvl);
  transpose_split<<<tg, blk, 0, stream>>>(Wo, wvh == nullptr ? nullptr : woh, wol);

  const int gC = (NCAT / 128) * (HID / 128);    // 1024 blocks (merged proj)
  const int gP = (NROW / 128) * (HID / 128);    // 512  blocks
  const int gS = (NROW / 128) * (NROW / 128);   // 4096 blocks

  // merged projections over cat (q,k split; v split transposed)
  gemm_bt<0, true, false, true><<<gC, blk, 0, stream>>>(cath, catl, nullptr, HID, wqh, wql, HID, bq, nullptr, qh, ql, HID, HID, 8);
  gemm_bt<0, true, false, true><<<gC, blk, 0, stream>>>(cath, catl, nullptr, HID, wkh, wkl, HID, bk, nullptr, kh, kl, HID, HID, 8);
  gemm_bt<0, true, true,  true><<<gC, blk, 0, stream>>>(cath, catl, nullptr, HID, wvh, wvl, HID, bv, nullptr, vth, vtl, NCAT, HID, 8);

  // raw logits straight into the weight output slots (fp32)
  // tts: q from text (rows NROW..), k from speech (rows 0..)
  gemm_bt<0, false, false, false><<<gS, blk, 0, stream>>>(qh + NH, ql + NH, nullptr, HID, kh, kl, HID, nullptr, tts_w, nullptr, nullptr, NROW, HID, 64);
  // stt: q from speech (rows 0..), k from text (rows NROW..)
  gemm_bt<0, false, false, false><<<gS, blk, 0, stream>>>(qh, ql, nullptr, HID, kh + NH, kl + NH, HID, nullptr, stt_w, nullptr, nullptr, NROW, HID, 64);

  if (pathA) {
    softmax_rows<true><<<NROW, blk, 0, stream>>>(tts_w, (ushort4*)wsh, (ushort4*)wsl);
    gemm_bt<0, false, false, true><<<gP, blk, 0, stream>>>(wsh, wsl, nullptr, NROW, vth, vtl, NCAT, nullptr, nullptr, c1h, c1l, HID, NROW, 8);
    gemm_bt<0, true, false, false><<<gP, blk, 0, stream>>>(c1h, c1l, nullptr, HID, woh, wol, HID, bo, tts_out, nullptr, nullptr, HID, HID, 8);
    softmax_rows<true><<<NROW, blk, 0, stream>>>(stt_w, (ushort4*)wsh, (ushort4*)wsl);
    gemm_bt<0, false, false, true><<<gP, blk, 0, stream>>>(wsh, wsl, nullptr, NROW, vth + NROW, vtl + NROW, NCAT, nullptr, nullptr, c2h, c2l, HID, NROW, 8);
    gemm_bt<0, true, false, false><<<gP, blk, 0, stream>>>(c2h, c2l, nullptr, HID, woh, wol, HID, bo, stt_out, nullptr, nullptr, HID, HID, 8);
  } else {
    softmax_rows<false><<<NROW, blk, 0, stream>>>(tts_w, nullptr, nullptr);
    softmax_rows<false><<<NROW, blk, 0, stream>>>(stt_w, nullptr, nullptr);
    gemm_bt<1, false, false, true><<<gP, blk, 0, stream>>>(nullptr, nullptr, tts_w, NROW, vth, vtl, NCAT, nullptr, nullptr, c1h, c1l, HID, NROW, 8);
    gemm_bt<0, true, false, false><<<gP, blk, 0, stream>>>(c1h, c1l, nullptr, HID, woh, wol, HID, bo, tts_out, nullptr, nullptr, HID, HID, 8);
    gemm_bt<1, false, false, true><<<gP, blk, 0, stream>>>(nullptr, nullptr, stt_w, NROW, vth + NROW, vtl + NROW, NCAT, nullptr, nullptr, c2h, c2l, HID, NROW, 8);
    gemm_bt<0, true, false, false><<<gP, blk, 0, stream>>>(c2h, c2l, nullptr, HID, woh, wol, HID, bo, stt_out, nullptr, nullptr, HID, HID, 8);
  }
}

// Round 4
// 2804.403 us; speedup vs baseline: 1.1249x; 1.1249x over previous
//
#include <hip/hip_runtime.h>

#define HID 1024
#define NROW 8192
#define NCAT 16384   // [speech; text] concatenated rows

typedef unsigned short u16;
typedef short s16x8 __attribute__((ext_vector_type(8)));
typedef float f32x4 __attribute__((ext_vector_type(4)));

// ---- fp32 ~= bf16(hi) + bf16(lo), both round-to-nearest-even ----
__device__ __forceinline__ u16 rtn16(float x) {
  unsigned xb = __builtin_bit_cast(unsigned, x);
  return (u16)((xb + 0x7fffu + ((xb >> 16) & 1u)) >> 16);
}
__device__ __forceinline__ float fromh(u16 h) {
  return __builtin_bit_cast(float, (unsigned)h << 16);
}
__device__ __forceinline__ void split2(float x, u16 &h, u16 &l) {
  h = rtn16(x);
  l = rtn16(x - fromh(h));
}

// async global->LDS, 16B/lane; LDS dest must be wave-uniform base + lane*16
__device__ __forceinline__ void gl16(const void* g, void* l) {
  __builtin_amdgcn_global_load_lds(
      (const __attribute__((address_space(1))) unsigned int*)g,
      (__attribute__((address_space(3))) unsigned int*)l, 16, 0, 0);
}

template<int N> __device__ __forceinline__ void waitvm() {
  if constexpr (N == 3) asm volatile("s_waitcnt vmcnt(3)" ::: "memory");
  else if constexpr (N == 4) asm volatile("s_waitcnt vmcnt(4)" ::: "memory");
  else if constexpr (N == 5) asm volatile("s_waitcnt vmcnt(5)" ::: "memory");
  else if constexpr (N == 6) asm volatile("s_waitcnt vmcnt(6)" ::: "memory");
}

// stage one plane chunk (ROWS x 32 u16) of tile at k0 into ldsbase, with the
// quarter-swizzle applied on the GLOBAL side (rule #21: lds dest stays linear)
template<int ROWS>
__device__ __forceinline__ void stage_chunk(const u16* __restrict__ pg, int ld,
                                            int grow0, int k0, u16* ldsbase, int tid)
{
  constexpr int NLD = (ROWS * 32) / (512 * 8);  // 16B per thread per instr
  #pragma unroll
  for (int j = 0; j < NLD; ++j) {
    int idx = tid + j * 512;
    int row = idx >> 2, q = idx & 3;
    int qs = q ^ ((row >> 1) & 3);
    gl16(pg + (size_t)(grow0 + row) * ld + k0 + qs * 8, ldsbase + (size_t)idx * 8);
  }
}

// read NFR 16x16x32 fragments (rows w0+i*16+fr) from a swizzled plane chunk
template<int NFR>
__device__ __forceinline__ void read_frags(s16x8* f, const u16* base,
                                           int w0, int fr, int fq)
{
  #pragma unroll
  for (int i = 0; i < NFR; ++i) {
    int r = w0 + i * 16 + fr;
    f[i] = *(const s16x8*)(base + r * 32 + ((fq ^ ((r >> 1) & 3)) << 3));
  }
}

// =====================================================================
// Big-GEMM: C[M,N] = A[M,K] @ Bt[N,K]^T, split-bf16 fp32 emulation.
// BM=256 fixed. 8 waves (WMv x WNv), per-wave (256/WMv)x(BN/WNv).
// 3 phases per K-tile (BK=32): P1 AhBh, P2 AhBl, P3 AlBh, each phase:
//   vmcnt(counted) -> s_barrier -> issue next-tile gloads -> ds_read -> MFMA
// Double-buffered LDS; prefetch depth = 1 tile; vmcnt never 0 in loop.
// =====================================================================
template<int BN, int WMv, int WNv, int MF, int NF, bool OUT_SPLIT>
__global__ void __launch_bounds__(512, 2)
gemm_big(const u16* __restrict__ Agh, const u16* __restrict__ Agl, int lda,
         const u16* __restrict__ Bgh, const u16* __restrict__ Bgl, int ldb,
         float* __restrict__ Cf, u16* __restrict__ Ch, u16* __restrict__ Cl,
         int ldc, int K, int tiles_n)
{
  constexpr int BM = 256;
  constexpr int ASZ = BM * 32;          // u16 per A plane chunk
  constexpr int BSZ = BN * 32;
  constexpr int BUF = 2 * ASZ + 2 * BSZ;
  constexpr int AL_ = (ASZ * 2) / (512 * 16);   // gload instrs per A chunk (2)
  constexpr int BL_ = (BSZ * 2) / (512 * 16);   // 2 (BN=256) or 1 (BN=128)
  constexpr int TL  = 2 * AL_ + 2 * BL_;        // per-tile gload instrs
  constexpr int W1 = TL - (AL_ + BL_);          // P1 wait
  constexpr int W2 = TL - BL_;                  // P2 wait
  constexpr int W3 = AL_ + 2 * BL_;             // P3 wait

  __shared__ __align__(16) u16 lds[2 * BUF];

  const int tid = threadIdx.x;
  const unsigned nwg = gridDim.x;
  const unsigned bid = blockIdx.x;
  const unsigned swz = (bid & 7u) * (nwg >> 3) + (bid >> 3);
  const int bm = (int)(swz / (unsigned)tiles_n) * BM;
  const int bn = (int)(swz % (unsigned)tiles_n) * BN;

  const int w = tid >> 6, lane = tid & 63;
  const int wr = (w / WNv) * (BM / WMv);
  const int wc = (w % WNv) * (BN / WNv);
  const int fr = lane & 15, fq = lane >> 4;

  f32x4 acc[MF][NF] = {};
  const int nt = K / 32;

  // prologue: tile 0 in consumption order Ah, Bh, Bl, Al
  stage_chunk<BM>(Agh, lda, bm, 0, lds + 0,             tid);
  stage_chunk<BN>(Bgh, ldb, bn, 0, lds + 2 * ASZ,       tid);
  stage_chunk<BN>(Bgl, ldb, bn, 0, lds + 2 * ASZ + BSZ, tid);
  stage_chunk<BM>(Agl, lda, bm, 0, lds + ASZ,           tid);

  int cur = 0;
  for (int t = 0; t < nt; ++t) {
    const int k0n = (t + 1 == nt) ? 0 : (t + 1) * 32;   // wrap: harmless reload
    const int nxt = cur ^ 1;
    u16* cb = lds + cur * BUF;
    u16* nb = lds + nxt * BUF;
    s16x8 ah[MF], bh[NF];

    // ---- P1: Ah * Bh ----
    waitvm<W1>();
    __builtin_amdgcn_s_barrier();
    __builtin_amdgcn_sched_barrier(0);
    stage_chunk<BM>(Agh, lda, bm, k0n, nb + 0,       tid);
    stage_chunk<BN>(Bgh, ldb, bn, k0n, nb + 2 * ASZ, tid);
    read_frags<MF>(ah, cb + 0,       wr, fr, fq);
    read_frags<NF>(bh, cb + 2 * ASZ, wc, fr, fq);
    __builtin_amdgcn_s_setprio(1);
    #pragma unroll
    for (int m = 0; m < MF; ++m)
      #pragma unroll
      for (int n = 0; n < NF; ++n)
        acc[m][n] = __builtin_amdgcn_mfma_f32_16x16x32_bf16(ah[m], bh[n], acc[m][n], 0, 0, 0);
    __builtin_amdgcn_s_setprio(0);

    // ---- P2: Ah * Bl ----
    waitvm<W2>();
    __builtin_amdgcn_s_barrier();
    __builtin_amdgcn_sched_barrier(0);
    stage_chunk<BN>(Bgl, ldb, bn, k0n, nb + 2 * ASZ + BSZ, tid);
    {
      s16x8 bl[NF];
      read_frags<NF>(bl, cb + 2 * ASZ + BSZ, wc, fr, fq);
      __builtin_amdgcn_s_setprio(1);
      #pragma unroll
      for (int m = 0; m < MF; ++m)
        #pragma unroll
        for (int n = 0; n < NF; ++n)
          acc[m][n] = __builtin_amdgcn_mfma_f32_16x16x32_bf16(ah[m], bl[n], acc[m][n], 0, 0, 0);
      __builtin_amdgcn_s_setprio(0);
    }

    // ---- P3: Al * Bh ----
    waitvm<W3>();
    __builtin_amdgcn_s_barrier();
    __builtin_amdgcn_sched_barrier(0);
    stage_chunk<BM>(Agl, lda, bm, k0n, nb + ASZ, tid);
    {
      s16x8 al[MF];
      read_frags<MF>(al, cb + ASZ, wr, fr, fq);
      __builtin_amdgcn_s_setprio(1);
      #pragma unroll
      for (int m = 0; m < MF; ++m)
        #pragma unroll
        for (int n = 0; n < NF; ++n)
          acc[m][n] = __builtin_amdgcn_mfma_f32_16x16x32_bf16(al[m], bh[n], acc[m][n], 0, 0, 0);
      __builtin_amdgcn_s_setprio(0);
    }
    cur = nxt;
  }

  // epilogue — C/D frag: col = fr, row = fq*4 + i  [m89-verified layout]
  #pragma unroll
  for (int m = 0; m < MF; ++m) {
    int row0 = bm + wr + m * 16 + fq * 4;
    #pragma unroll
    for (int n = 0; n < NF; ++n) {
      int col = bn + wc + n * 16 + fr;
      if constexpr (OUT_SPLIT) {
        #pragma unroll
        for (int i = 0; i < 4; ++i) {
          u16 h, l; split2(acc[m][n][i], h, l);
          Ch[(size_t)(row0 + i) * ldc + col] = h;
          Cl[(size_t)(row0 + i) * ldc + col] = l;
        }
      } else {
        #pragma unroll
        for (int i = 0; i < 4; ++i)
          Cf[(size_t)(row0 + i) * ldc + col] = acc[m][n][i];
      }
    }
  }
}

// =====================================================================
// Old validated 128x128 GEMM (kept for projections / out-proj / fallback)
// =====================================================================
template<int AMODE, bool ADD_BIAS, bool WRITE_T, bool OUT_SPLIT>
__global__ void __launch_bounds__(256, 2)
gemm_bt(const u16* __restrict__ Agh, const u16* __restrict__ Agl,
        const float* __restrict__ Agf, int lda,
        const u16* __restrict__ Bgh, const u16* __restrict__ Bgl, int ldb,
        const float* __restrict__ bias,
        float* __restrict__ Cf, u16* __restrict__ Ch, u16* __restrict__ Cl,
        int ldc, int K, int tiles_n)
{
  __shared__ __align__(16) u16 sAh[128 * 32];
  __shared__ __align__(16) u16 sAl[128 * 32];
  __shared__ __align__(16) u16 sBh[128 * 32];
  __shared__ __align__(16) u16 sBl[128 * 32];

  const int tid = threadIdx.x;
  const unsigned nwg = gridDim.x;
  const unsigned bid = blockIdx.x;
  const unsigned swz = (bid & 7u) * (nwg >> 3) + (bid >> 3);
  const int bm = (int)(swz / (unsigned)tiles_n) * 128;
  const int bn = (int)(swz % (unsigned)tiles_n) * 128;

  const int wave = tid >> 6;
  const int lane = tid & 63;
  const int wr = (wave >> 1) * 64;
  const int wc = (wave & 1) * 64;
  const int fr = lane & 15;
  const int fq = lane >> 4;

  const u16* pAh[2]; const u16* pAl[2];
  const u16* pBh[2]; const u16* pBl[2];
  u16* dA[2]; u16* dB[2];
  #pragma unroll
  for (int j = 0; j < 2; ++j) {
    int c = tid + j * 256;
    int row = c >> 2;
    int kc = (c & 3) * 8;
    if constexpr (AMODE == 0) {
      pAh[j] = Agh + (size_t)(bm + row) * lda + kc;
      pAl[j] = Agl + (size_t)(bm + row) * lda + kc;
    }
    pBh[j] = Bgh + (size_t)(bn + row) * ldb + kc;
    pBl[j] = Bgl + (size_t)(bn + row) * ldb + kc;
    dA[j] = (u16*)((char*)sAh + (size_t)c * 16);
    dB[j] = (u16*)((char*)sBh + (size_t)c * 16);
  }
  const size_t loOffA = (char*)sAl - (char*)sAh;
  const size_t loOffB = (char*)sBl - (char*)sBh;

  f32x4 acc[4][4] = {};

  for (int k0 = 0; k0 < K; k0 += 32) {
    if constexpr (AMODE == 0) {
      #pragma unroll
      for (int j = 0; j < 2; ++j) {
        gl16(pAh[j] + k0, dA[j]);
        gl16(pAl[j] + k0, (char*)dA[j] + loOffA);
        gl16(pBh[j] + k0, dB[j]);
        gl16(pBl[j] + k0, (char*)dB[j] + loOffB);
      }
    } else {
      #pragma unroll
      for (int j = 0; j < 2; ++j) {
        gl16(pBh[j] + k0, dB[j]);
        gl16(pBl[j] + k0, (char*)dB[j] + loOffB);
      }
      const int row = tid >> 1;
      const int c0 = (tid & 1) * 16;
      const float4* src = (const float4*)(Agf + (size_t)(bm + row) * lda + k0 + c0);
      u16* dh = &sAh[row * 32 + c0];
      u16* dl = &sAl[row * 32 + c0];
      #pragma unroll
      for (int q = 0; q < 4; ++q) {
        float4 v = src[q];
        ushort4 h4, l4;
        split2(v.x, h4.x, l4.x); split2(v.y, h4.y, l4.y);
        split2(v.z, h4.z, l4.z); split2(v.w, h4.w, l4.w);
        ((ushort4*)dh)[q] = h4;
        ((ushort4*)dl)[q] = l4;
      }
    }
    __syncthreads();

    s16x8 ah[4], al[4], bh[4], bl[4];
    #pragma unroll
    for (int m = 0; m < 4; ++m) {
      int r = (wr + m * 16 + fr) * 32 + fq * 8;
      ah[m] = *(const s16x8*)&sAh[r];
      al[m] = *(const s16x8*)&sAl[r];
    }
    #pragma unroll
    for (int n = 0; n < 4; ++n) {
      int r = (wc + n * 16 + fr) * 32 + fq * 8;
      bh[n] = *(const s16x8*)&sBh[r];
      bl[n] = *(const s16x8*)&sBl[r];
    }
    #pragma unroll
    for (int m = 0; m < 4; ++m)
      #pragma unroll
      for (int n = 0; n < 4; ++n) {
        acc[m][n] = __builtin_amdgcn_mfma_f32_16x16x32_bf16(ah[m], bh[n], acc[m][n], 0, 0, 0);
        acc[m][n] = __builtin_amdgcn_mfma_f32_16x16x32_bf16(ah[m], bl[n], acc[m][n], 0, 0, 0);
        acc[m][n] = __builtin_amdgcn_mfma_f32_16x16x32_bf16(al[m], bh[n], acc[m][n], 0, 0, 0);
      }
    __syncthreads();
  }

  #pragma unroll
  for (int m = 0; m < 4; ++m) {
    int row0 = bm + wr + m * 16 + fq * 4;
    #pragma unroll
    for (int n = 0; n < 4; ++n) {
      int col = bn + wc + n * 16 + fr;
      f32x4 v = acc[m][n];
      if (ADD_BIAS) v = v + bias[col];
      if constexpr (WRITE_T) {
        ushort4 h4, l4;
        split2(v[0], h4.x, l4.x); split2(v[1], h4.y, l4.y);
        split2(v[2], h4.z, l4.z); split2(v[3], h4.w, l4.w);
        *(ushort4*)&Ch[(size_t)col * ldc + row0] = h4;
        *(ushort4*)&Cl[(size_t)col * ldc + row0] = l4;
      } else if constexpr (OUT_SPLIT) {
        #pragma unroll
        for (int i = 0; i < 4; ++i) {
          u16 h, l; split2(v[i], h, l);
          Ch[(size_t)(row0 + i) * ldc + col] = h;
          Cl[(size_t)(row0 + i) * ldc + col] = l;
        }
      } else {
        #pragma unroll
        for (int i = 0; i < 4; ++i)
          Cf[(size_t)(row0 + i) * ldc + col] = v[i];
      }
    }
  }
}

// =====================================================================
// in-place row softmax (rows of 8192); optionally emit hi/lo split planes
// =====================================================================
template<bool SPLIT>
__global__ void __launch_bounds__(256)
softmax_rows(float* __restrict__ S, ushort4* __restrict__ Wh, ushort4* __restrict__ Wl)
{
  __shared__ float redm[4];
  __shared__ float reds[4];
  const int tid = threadIdx.x;
  float* p = S + (size_t)blockIdx.x * NROW;

  float4 v[8];
  float mx = -3.4e38f;
  #pragma unroll
  for (int i = 0; i < 8; ++i) {
    v[i] = *(const float4*)(p + ((tid + i * 256) << 2));
    mx = fmaxf(mx, fmaxf(fmaxf(v[i].x, v[i].y), fmaxf(v[i].z, v[i].w)));
  }
  #pragma unroll
  for (int off = 32; off > 0; off >>= 1)
    mx = fmaxf(mx, __shfl_xor(mx, off));
  if ((tid & 63) == 0) redm[tid >> 6] = mx;
  __syncthreads();
  mx = fmaxf(fmaxf(redm[0], redm[1]), fmaxf(redm[2], redm[3]));

  const float c = 1.44269504088896340736f;
  float s = 0.0f;
  #pragma unroll
  for (int i = 0; i < 8; ++i) {
    v[i].x = exp2f((v[i].x - mx) * c);
    v[i].y = exp2f((v[i].y - mx) * c);
    v[i].z = exp2f((v[i].z - mx) * c);
    v[i].w = exp2f((v[i].w - mx) * c);
    s += v[i].x + v[i].y + v[i].z + v[i].w;
  }
  #pragma unroll
  for (int off = 32; off > 0; off >>= 1)
    s += __shfl_xor(s, off);
  if ((tid & 63) == 0) reds[tid >> 6] = s;
  __syncthreads();
  s = reds[0] + reds[1] + reds[2] + reds[3];
  const float inv = 1.0f / s;
  const size_t rb4 = (size_t)blockIdx.x * (NROW / 4);

  #pragma unroll
  for (int i = 0; i < 8; ++i) {
    float4 w4;
    w4.x = v[i].x * inv; w4.y = v[i].y * inv;
    w4.z = v[i].z * inv; w4.w = v[i].w * inv;
    *(float4*)(p + ((tid + i * 256) << 2)) = w4;
    if constexpr (SPLIT) {
      ushort4 h4, l4;
      split2(w4.x, h4.x, l4.x); split2(w4.y, h4.y, l4.y);
      split2(w4.z, h4.z, l4.z); split2(w4.w, h4.w, l4.w);
      size_t o = rb4 + tid + i * 256;
      Wh[o] = h4;
      Wl[o] = l4;
    }
  }
}

__global__ void __launch_bounds__(256)
conv_split(const float4* __restrict__ in, const float* __restrict__ wp,
           ushort4* __restrict__ oh, ushort4* __restrict__ ol)
{
  const int i = blockIdx.x * 256 + threadIdx.x;
  const float w = wp[0];
  float a = in[i * 4 + 0].x * w, b = in[i * 4 + 1].x * w;
  float c = in[i * 4 + 2].x * w, d = in[i * 4 + 3].x * w;
  ushort4 h4, l4;
  split2(a, h4.x, l4.x); split2(b, h4.y, l4.y);
  split2(c, h4.z, l4.z); split2(d, h4.w, l4.w);
  oh[i] = h4;
  ol[i] = l4;
}

__global__ void __launch_bounds__(256)
split_mat(const float4* __restrict__ in, ushort4* __restrict__ oh, ushort4* __restrict__ ol)
{
  const int i = blockIdx.x * 256 + threadIdx.x;
  float4 v = in[i];
  ushort4 h4, l4;
  split2(v.x, h4.x, l4.x); split2(v.y, h4.y, l4.y);
  split2(v.z, h4.z, l4.z); split2(v.w, h4.w, l4.w);
  oh[i] = h4;
  ol[i] = l4;
}

__global__ void __launch_bounds__(256)
transpose_split(const float* __restrict__ in, u16* __restrict__ oh, u16* __restrict__ ol)
{
  __shared__ float t[32][33];
  const int tx = threadIdx.x & 31, ty = threadIdx.x >> 5;
  const int bx = blockIdx.x * 32, by = blockIdx.y * 32;
  #pragma unroll
  for (int i = 0; i < 32; i += 8)
    t[ty + i][tx] = in[(size_t)(by + ty + i) * HID + bx + tx];
  __syncthreads();
  #pragma unroll
  for (int i = 0; i < 32; i += 8) {
    float v = t[tx][ty + i];
    size_t o = (size_t)(bx + ty + i) * HID + by + tx;
    u16 h, l; split2(v, h, l);
    oh[o] = h;
    ol[o] = l;
  }
}

extern "C" void kernel_launch(void* const* d_in, const int* in_sizes, int n_in,
                              void* d_out, int out_size, void* d_ws, size_t ws_size,
                              hipStream_t stream)
{
  (void)in_sizes; (void)n_in; (void)out_size;
  const float* speech_embed = (const float*)d_in[0];
  const float* text  = (const float*)d_in[1];
  const float* convw = (const float*)d_in[2];
  const float* Wq = (const float*)d_in[3];
  const float* bq = (const float*)d_in[4];
  const float* Wk = (const float*)d_in[5];
  const float* bk = (const float*)d_in[6];
  const float* Wv = (const float*)d_in[7];
  const float* bv = (const float*)d_in[8];
  const float* Wo = (const float*)d_in[9];
  const float* bo = (const float*)d_in[10];
  float* out = (float*)d_out;

  const size_t NH = (size_t)NROW * HID;
  const size_t NN = (size_t)NROW * NROW;
  const size_t HH = (size_t)HID * HID;

  u16* base = (u16*)d_ws;
  size_t off = 0;
  auto alloc = [&](size_t n) { u16* p = base + off; off += n; return p; };
  u16 *cath = alloc(2 * NH), *catl = alloc(2 * NH);
  u16 *sph = cath,       *spl = catl;
  u16 *txh = cath + NH,  *txl = catl + NH;
  u16 *wqh = alloc(HH), *wql = alloc(HH);
  u16 *wkh = alloc(HH), *wkl = alloc(HH);
  u16 *wvh = alloc(HH), *wvl = alloc(HH);
  u16 *woh = alloc(HH), *wol = alloc(HH);
  u16 *qh = alloc(2 * NH), *ql = alloc(2 * NH);   // [NCAT][HID]
  u16 *kh = alloc(2 * NH), *kl = alloc(2 * NH);
  u16 *vth = alloc(2 * NH), *vtl = alloc(2 * NH); // [HID][NCAT]
  u16 *c1h = qh,      *c1l = ql;                  // ctx reuses dead q planes
  u16 *c2h = qh + NH, *c2l = ql + NH;
  const bool pathA = ((off + 2 * NN) * sizeof(u16)) <= ws_size;
  u16 *wsh = nullptr, *wsl = nullptr;
  if (pathA) { wsh = alloc(NN); wsl = alloc(NN); }

  float* tts_out = out;
  float* tts_w   = out + NH;
  float* stt_out = tts_w + NN;
  float* stt_w   = stt_out + NH;

  const dim3 blk(256);
  const dim3 blk5(512);

  conv_split<<<NH / 1024, blk, 0, stream>>>((const float4*)speech_embed, convw,
                                            (ushort4*)sph, (ushort4*)spl);
  split_mat<<<NH / 1024, blk, 0, stream>>>((const float4*)text, (ushort4*)txh, (ushort4*)txl);
  const dim3 tg(32, 32);
  transpose_split<<<tg, blk, 0, stream>>>(Wq, wqh, wql);
  transpose_split<<<tg, blk, 0, stream>>>(Wk, wkh, wkl);
  transpose_split<<<tg, blk, 0, stream>>>(Wv, wvh, wvl);
  transpose_split<<<tg, blk, 0, stream>>>(Wo, woh, wol);

  const int gC = (NCAT / 128) * (HID / 128);    // 1024 (merged proj, old kernel)
  const int gP = (NROW / 128) * (HID / 128);    // 512
  const int gS_big = (NROW / 256) * (NROW / 256);  // 1024 (new 256x256)
  const int gPV_big = (NROW / 256) * (HID / 128);  // 256  (new 256x128)

  // merged projections (old kernel)
  gemm_bt<0, true, false, true><<<gC, blk, 0, stream>>>(cath, catl, nullptr, HID, wqh, wql, HID, bq, nullptr, qh, ql, HID, HID, 8);
  gemm_bt<0, true, false, true><<<gC, blk, 0, stream>>>(cath, catl, nullptr, HID, wkh, wkl, HID, bk, nullptr, kh, kl, HID, HID, 8);
  gemm_bt<0, true, true,  true><<<gC, blk, 0, stream>>>(cath, catl, nullptr, HID, wvh, wvl, HID, bv, nullptr, vth, vtl, NCAT, HID, 8);

  // raw logits (new 256x256 3-phase kernel) into weight output slots
  gemm_big<256, 2, 4, 8, 4, false><<<gS_big, blk5, 0, stream>>>(
      qh + NH, ql + NH, HID, kh, kl, HID, tts_w, nullptr, nullptr, NROW, HID, 32);
  gemm_big<256, 2, 4, 8, 4, false><<<gS_big, blk5, 0, stream>>>(
      qh, ql, HID, kh + NH, kl + NH, HID, stt_w, nullptr, nullptr, NROW, HID, 32);

  if (pathA) {
    softmax_rows<true><<<NROW, blk, 0, stream>>>(tts_w, (ushort4*)wsh, (ushort4*)wsl);
    gemm_big<128, 4, 2, 4, 4, true><<<gPV_big, blk5, 0, stream>>>(
        wsh, wsl, NROW, vth, vtl, NCAT, nullptr, c1h, c1l, HID, NROW, 8);
    gemm_bt<0, true, false, false><<<gP, blk, 0, stream>>>(c1h, c1l, nullptr, HID, woh, wol, HID, bo, tts_out, nullptr, nullptr, HID, HID, 8);
    softmax_rows<true><<<NROW, blk, 0, stream>>>(stt_w, (ushort4*)wsh, (ushort4*)wsl);
    gemm_big<128, 4, 2, 4, 4, true><<<gPV_big, blk5, 0, stream>>>(
        wsh, wsl, NROW, vth + NROW, vtl + NROW, NCAT, nullptr, c2h, c2l, HID, NROW, 8);
    gemm_bt<0, true, false, false><<<gP, blk, 0, stream>>>(c2h, c2l, nullptr, HID, woh, wol, HID, bo, stt_out, nullptr, nullptr, HID, HID, 8);
  } else {
    softmax_rows<false><<<NROW, blk, 0, stream>>>(tts_w, nullptr, nullptr);
    softmax_rows<false><<<NROW, blk, 0, stream>>>(stt_w, nullptr, nullptr);
    gemm_bt<1, false, false, true><<<gP, blk, 0, stream>>>(nullptr, nullptr, tts_w, NROW, vth, vtl, NCAT, nullptr, nullptr, c1h, c1l, HID, NROW, 8);
    gemm_bt<0, true, false, false><<<gP, blk, 0, stream>>>(c1h, c1l, nullptr, HID, woh, wol, HID, bo, tts_out, nullptr, nullptr, HID, HID, 8);
    gemm_bt<1, false, false, true><<<gP, blk, 0, stream>>>(nullptr, nullptr, stt_w, NROW, vth + NROW, vtl + NROW, NCAT, nullptr, nullptr, c2h, c2l, HID, NROW, 8);
    gemm_bt<0, true, false, false><<<gP, blk, 0, stream>>>(c2h, c2l, nullptr, HID, woh, wol, HID, bo, stt_out, nullptr, nullptr, HID, HID, 8);
  }
}

// Round 5
// 2324.725 us; speedup vs baseline: 1.3570x; 1.2063x over previous
//
#include <hip/hip_runtime.h>

#define HID 1024
#define NROW 8192
#define NCAT 16384   // [speech; text] concatenated rows

typedef unsigned short u16;
typedef short s16x8 __attribute__((ext_vector_type(8)));
typedef float f32x4 __attribute__((ext_vector_type(4)));

// ---- fp32 ~= bf16(hi) + bf16(lo), both round-to-nearest-even ----
__device__ __forceinline__ u16 rtn16(float x) {
  unsigned xb = __builtin_bit_cast(unsigned, x);
  return (u16)((xb + 0x7fffu + ((xb >> 16) & 1u)) >> 16);
}
__device__ __forceinline__ float fromh(u16 h) {
  return __builtin_bit_cast(float, (unsigned)h << 16);
}
__device__ __forceinline__ void split2(float x, u16 &h, u16 &l) {
  h = rtn16(x);
  l = rtn16(x - fromh(h));
}

// async global->LDS, 16B/lane; LDS dest must be wave-uniform base + lane*16
__device__ __forceinline__ void gl16(const void* g, void* l) {
  __builtin_amdgcn_global_load_lds(
      (const __attribute__((address_space(1))) unsigned int*)g,
      (__attribute__((address_space(3))) unsigned int*)l, 16, 0, 0);
}

template<int N> __device__ __forceinline__ void waitvm() {
  if constexpr (N == 3) asm volatile("s_waitcnt vmcnt(3)" ::: "memory");
  else if constexpr (N == 4) asm volatile("s_waitcnt vmcnt(4)" ::: "memory");
  else if constexpr (N == 5) asm volatile("s_waitcnt vmcnt(5)" ::: "memory");
  else if constexpr (N == 6) asm volatile("s_waitcnt vmcnt(6)" ::: "memory");
}

// stage one plane chunk (ROWS x 32 u16) at k0 into ldsbase; quarter-swizzle
// applied on the GLOBAL side (rule #21: lds dest stays linear)
template<int ROWS>
__device__ __forceinline__ void stage_chunk(const u16* __restrict__ pg, int ld,
                                            int grow0, int k0, u16* ldsbase, int tid)
{
  constexpr int NLD = (ROWS * 32) / (512 * 8);
  #pragma unroll
  for (int j = 0; j < NLD; ++j) {
    int idx = tid + j * 512;
    int row = idx >> 2, q = idx & 3;
    int qs = q ^ ((row >> 1) & 3);
    gl16(pg + (size_t)(grow0 + row) * ld + k0 + qs * 8, ldsbase + (size_t)idx * 8);
  }
}

// read NFR 16x16x32 fragments from a swizzled plane chunk
template<int NFR>
__device__ __forceinline__ void read_frags(s16x8* f, const u16* base,
                                           int w0, int fr, int fq)
{
  #pragma unroll
  for (int i = 0; i < NFR; ++i) {
    int r = w0 + i * 16 + fr;
    f[i] = *(const s16x8*)(base + r * 32 + ((fq ^ ((r >> 1) & 3)) << 3));
  }
}

// =====================================================================
// Big-GEMM (3-plane fp32 emulation): C = A @ Bt^T (+bias).
// BM=256, 8 waves, 3 phases/K-tile with counted vmcnt (validated r4).
// OUTMODE: 0 = fp32 [M][N]; 1 = hi/lo split planes [M][N].
// =====================================================================
template<int BN, int WMv, int WNv, int MF, int NF, bool ADD_BIAS, int OUTMODE>
__global__ void __launch_bounds__(512, 2)
gemm_big(const u16* __restrict__ Agh, const u16* __restrict__ Agl, int lda,
         const u16* __restrict__ Bgh, const u16* __restrict__ Bgl, int ldb,
         const float* __restrict__ bias,
         float* __restrict__ Cf, u16* __restrict__ Ch, u16* __restrict__ Cl,
         int ldc, int K, int tiles_n)
{
  constexpr int BM = 256;
  constexpr int ASZ = BM * 32;
  constexpr int BSZ = BN * 32;
  constexpr int BUF = 2 * ASZ + 2 * BSZ;
  constexpr int AL_ = (ASZ * 2) / (512 * 16);
  constexpr int BL_ = (BSZ * 2) / (512 * 16);
  constexpr int TL  = 2 * AL_ + 2 * BL_;
  constexpr int W1 = TL - (AL_ + BL_);
  constexpr int W2 = TL - BL_;
  constexpr int W3 = AL_ + 2 * BL_;

  __shared__ __align__(16) u16 lds[2 * BUF];

  const int tid = threadIdx.x;
  const unsigned nwg = gridDim.x;
  const unsigned bid = blockIdx.x;
  const unsigned swz = (bid & 7u) * (nwg >> 3) + (bid >> 3);
  const int bm = (int)(swz / (unsigned)tiles_n) * BM;
  const int bn = (int)(swz % (unsigned)tiles_n) * BN;

  const int w = tid >> 6, lane = tid & 63;
  const int wr = (w / WNv) * (BM / WMv);
  const int wc = (w % WNv) * (BN / WNv);
  const int fr = lane & 15, fq = lane >> 4;

  f32x4 acc[MF][NF] = {};
  const int nt = K / 32;

  stage_chunk<BM>(Agh, lda, bm, 0, lds + 0,             tid);
  stage_chunk<BN>(Bgh, ldb, bn, 0, lds + 2 * ASZ,       tid);
  stage_chunk<BN>(Bgl, ldb, bn, 0, lds + 2 * ASZ + BSZ, tid);
  stage_chunk<BM>(Agl, lda, bm, 0, lds + ASZ,           tid);

  int cur = 0;
  for (int t = 0; t < nt; ++t) {
    const int k0n = (t + 1 == nt) ? 0 : (t + 1) * 32;   // wrap: harmless reload
    const int nxt = cur ^ 1;
    u16* cb = lds + cur * BUF;
    u16* nb = lds + nxt * BUF;
    s16x8 ah[MF], bh[NF];

    // ---- P1: Ah * Bh ----
    waitvm<W1>();
    __builtin_amdgcn_s_barrier();
    __builtin_amdgcn_sched_barrier(0);
    stage_chunk<BM>(Agh, lda, bm, k0n, nb + 0,       tid);
    stage_chunk<BN>(Bgh, ldb, bn, k0n, nb + 2 * ASZ, tid);
    read_frags<MF>(ah, cb + 0,       wr, fr, fq);
    read_frags<NF>(bh, cb + 2 * ASZ, wc, fr, fq);
    __builtin_amdgcn_s_setprio(1);
    #pragma unroll
    for (int m = 0; m < MF; ++m)
      #pragma unroll
      for (int n = 0; n < NF; ++n)
        acc[m][n] = __builtin_amdgcn_mfma_f32_16x16x32_bf16(ah[m], bh[n], acc[m][n], 0, 0, 0);
    __builtin_amdgcn_s_setprio(0);

    // ---- P2: Ah * Bl ----
    waitvm<W2>();
    __builtin_amdgcn_s_barrier();
    __builtin_amdgcn_sched_barrier(0);
    stage_chunk<BN>(Bgl, ldb, bn, k0n, nb + 2 * ASZ + BSZ, tid);
    {
      s16x8 bl[NF];
      read_frags<NF>(bl, cb + 2 * ASZ + BSZ, wc, fr, fq);
      __builtin_amdgcn_s_setprio(1);
      #pragma unroll
      for (int m = 0; m < MF; ++m)
        #pragma unroll
        for (int n = 0; n < NF; ++n)
          acc[m][n] = __builtin_amdgcn_mfma_f32_16x16x32_bf16(ah[m], bl[n], acc[m][n], 0, 0, 0);
      __builtin_amdgcn_s_setprio(0);
    }

    // ---- P3: Al * Bh ----
    waitvm<W3>();
    __builtin_amdgcn_s_barrier();
    __builtin_amdgcn_sched_barrier(0);
    stage_chunk<BM>(Agl, lda, bm, k0n, nb + ASZ, tid);
    {
      s16x8 al[MF];
      read_frags<MF>(al, cb + ASZ, wr, fr, fq);
      __builtin_amdgcn_s_setprio(1);
      #pragma unroll
      for (int m = 0; m < MF; ++m)
        #pragma unroll
        for (int n = 0; n < NF; ++n)
          acc[m][n] = __builtin_amdgcn_mfma_f32_16x16x32_bf16(al[m], bh[n], acc[m][n], 0, 0, 0);
      __builtin_amdgcn_s_setprio(0);
    }
    cur = nxt;
  }

  #pragma unroll
  for (int m = 0; m < MF; ++m) {
    int row0 = bm + wr + m * 16 + fq * 4;
    #pragma unroll
    for (int n = 0; n < NF; ++n) {
      int col = bn + wc + n * 16 + fr;
      f32x4 v = acc[m][n];
      if (ADD_BIAS) v = v + bias[col];
      if constexpr (OUTMODE == 1) {
        #pragma unroll
        for (int i = 0; i < 4; ++i) {
          u16 h, l; split2(v[i], h, l);
          Ch[(size_t)(row0 + i) * ldc + col] = h;
          Cl[(size_t)(row0 + i) * ldc + col] = l;
        }
      } else {
        #pragma unroll
        for (int i = 0; i < 4; ++i)
          Cf[(size_t)(row0 + i) * ldc + col] = v[i];
      }
    }
  }
}

// =====================================================================
// 128x128 GEMM (m97 structure). NPLANES=3: fp32 emulation. NPLANES=1:
// plain bf16 (hi planes only) — used where precision analysis allows
// (PV, v-proj, out-proj: all O(1) post-softmax quantities).
// AMODE 1: A is fp32, split during staging (fallback PV).
// OUTMODE: 0 fp32 [M][N]; 1 split both [M][N]; 2 split both T [N][M];
//          3 hi-only [M][N]; 4 hi-only T [N][M].
// =====================================================================
template<int NPLANES, int AMODE, bool ADD_BIAS, int OUTMODE>
__global__ void __launch_bounds__(256, 2)
gemm_bt(const u16* __restrict__ Agh, const u16* __restrict__ Agl,
        const float* __restrict__ Agf, int lda,
        const u16* __restrict__ Bgh, const u16* __restrict__ Bgl, int ldb,
        const float* __restrict__ bias,
        float* __restrict__ Cf, u16* __restrict__ Ch, u16* __restrict__ Cl,
        int ldc, int K, int tiles_n)
{
  constexpr int PL = 128 * 32;
  __shared__ __align__(16) u16 lds[(NPLANES == 3 ? 4 : 2) * PL];
  u16* const sAh = lds;
  u16* const sBh = lds + (NPLANES == 3 ? 2 : 1) * PL;
  // lo planes live at sAh+PL / sBh+PL when NPLANES==3

  const int tid = threadIdx.x;
  const unsigned nwg = gridDim.x;
  const unsigned bid = blockIdx.x;
  const unsigned swz = (bid & 7u) * (nwg >> 3) + (bid >> 3);
  const int bm = (int)(swz / (unsigned)tiles_n) * 128;
  const int bn = (int)(swz % (unsigned)tiles_n) * 128;

  const int wave = tid >> 6;
  const int lane = tid & 63;
  const int wr = (wave >> 1) * 64;
  const int wc = (wave & 1) * 64;
  const int fr = lane & 15;
  const int fq = lane >> 4;

  const u16* pAh[2]; const u16* pAl[2];
  const u16* pBh[2]; const u16* pBl[2];
  u16* dA[2]; u16* dB[2];
  #pragma unroll
  for (int j = 0; j < 2; ++j) {
    int c = tid + j * 256;
    int row = c >> 2;
    int kc = (c & 3) * 8;
    if constexpr (AMODE == 0) {
      pAh[j] = Agh + (size_t)(bm + row) * lda + kc;
      if constexpr (NPLANES == 3) pAl[j] = Agl + (size_t)(bm + row) * lda + kc;
    }
    pBh[j] = Bgh + (size_t)(bn + row) * ldb + kc;
    if constexpr (NPLANES == 3) pBl[j] = Bgl + (size_t)(bn + row) * ldb + kc;
    dA[j] = sAh + (size_t)c * 8;
    dB[j] = sBh + (size_t)c * 8;
  }

  f32x4 acc[4][4] = {};

  for (int k0 = 0; k0 < K; k0 += 32) {
    if constexpr (AMODE == 0) {
      #pragma unroll
      for (int j = 0; j < 2; ++j) {
        gl16(pAh[j] + k0, dA[j]);
        if constexpr (NPLANES == 3) gl16(pAl[j] + k0, dA[j] + PL);
        gl16(pBh[j] + k0, dB[j]);
        if constexpr (NPLANES == 3) gl16(pBl[j] + k0, dB[j] + PL);
      }
    } else {
      #pragma unroll
      for (int j = 0; j < 2; ++j) {
        gl16(pBh[j] + k0, dB[j]);
        if constexpr (NPLANES == 3) gl16(pBl[j] + k0, dB[j] + PL);
      }
      const int row = tid >> 1;
      const int c0 = (tid & 1) * 16;
      const float4* src = (const float4*)(Agf + (size_t)(bm + row) * lda + k0 + c0);
      u16* dh = sAh + row * 32 + c0;
      #pragma unroll
      for (int q = 0; q < 4; ++q) {
        float4 v = src[q];
        if constexpr (NPLANES == 3) {
          ushort4 h4, l4;
          split2(v.x, h4.x, l4.x); split2(v.y, h4.y, l4.y);
          split2(v.z, h4.z, l4.z); split2(v.w, h4.w, l4.w);
          ((ushort4*)dh)[q] = h4;
          ((ushort4*)(dh + PL))[q] = l4;
        } else {
          ((ushort4*)dh)[q] = make_ushort4(rtn16(v.x), rtn16(v.y), rtn16(v.z), rtn16(v.w));
        }
      }
    }
    __syncthreads();

    s16x8 ah[4], bh[4];
    #pragma unroll
    for (int m = 0; m < 4; ++m)
      ah[m] = *(const s16x8*)(sAh + (wr + m * 16 + fr) * 32 + fq * 8);
    #pragma unroll
    for (int n = 0; n < 4; ++n)
      bh[n] = *(const s16x8*)(sBh + (wc + n * 16 + fr) * 32 + fq * 8);

    if constexpr (NPLANES == 3) {
      s16x8 al[4], bl[4];
      #pragma unroll
      for (int m = 0; m < 4; ++m)
        al[m] = *(const s16x8*)(sAh + PL + (wr + m * 16 + fr) * 32 + fq * 8);
      #pragma unroll
      for (int n = 0; n < 4; ++n)
        bl[n] = *(const s16x8*)(sBh + PL + (wc + n * 16 + fr) * 32 + fq * 8);
      #pragma unroll
      for (int m = 0; m < 4; ++m)
        #pragma unroll
        for (int n = 0; n < 4; ++n) {
          acc[m][n] = __builtin_amdgcn_mfma_f32_16x16x32_bf16(ah[m], bh[n], acc[m][n], 0, 0, 0);
          acc[m][n] = __builtin_amdgcn_mfma_f32_16x16x32_bf16(ah[m], bl[n], acc[m][n], 0, 0, 0);
          acc[m][n] = __builtin_amdgcn_mfma_f32_16x16x32_bf16(al[m], bh[n], acc[m][n], 0, 0, 0);
        }
    } else {
      #pragma unroll
      for (int m = 0; m < 4; ++m)
        #pragma unroll
        for (int n = 0; n < 4; ++n)
          acc[m][n] = __builtin_amdgcn_mfma_f32_16x16x32_bf16(ah[m], bh[n], acc[m][n], 0, 0, 0);
    }
    __syncthreads();
  }

  // epilogue — C/D frag: col = fr, row = fq*4 + i  [m89-verified layout]
  #pragma unroll
  for (int m = 0; m < 4; ++m) {
    int row0 = bm + wr + m * 16 + fq * 4;
    #pragma unroll
    for (int n = 0; n < 4; ++n) {
      int col = bn + wc + n * 16 + fr;
      f32x4 v = acc[m][n];
      if (ADD_BIAS) v = v + bias[col];
      if constexpr (OUTMODE == 0) {
        #pragma unroll
        for (int i = 0; i < 4; ++i)
          Cf[(size_t)(row0 + i) * ldc + col] = v[i];
      } else if constexpr (OUTMODE == 1) {
        #pragma unroll
        for (int i = 0; i < 4; ++i) {
          u16 h, l; split2(v[i], h, l);
          Ch[(size_t)(row0 + i) * ldc + col] = h;
          Cl[(size_t)(row0 + i) * ldc + col] = l;
        }
      } else if constexpr (OUTMODE == 2) {
        ushort4 h4, l4;
        split2(v[0], h4.x, l4.x); split2(v[1], h4.y, l4.y);
        split2(v[2], h4.z, l4.z); split2(v[3], h4.w, l4.w);
        *(ushort4*)&Ch[(size_t)col * ldc + row0] = h4;
        *(ushort4*)&Cl[(size_t)col * ldc + row0] = l4;
      } else if constexpr (OUTMODE == 3) {
        #pragma unroll
        for (int i = 0; i < 4; ++i)
          Ch[(size_t)(row0 + i) * ldc + col] = rtn16(v[i]);
      } else {  // 4: hi-only transposed
        *(ushort4*)&Ch[(size_t)col * ldc + row0] =
            make_ushort4(rtn16(v[0]), rtn16(v[1]), rtn16(v[2]), rtn16(v[3]));
      }
    }
  }
}

// =====================================================================
// in-place row softmax (rows of 8192); optionally emit hi bf16 plane
// =====================================================================
template<bool EMITH>
__global__ void __launch_bounds__(256)
softmax_rows(float* __restrict__ S, ushort4* __restrict__ Wh)
{
  __shared__ float redm[4];
  __shared__ float reds[4];
  const int tid = threadIdx.x;
  float* p = S + (size_t)blockIdx.x * NROW;

  float4 v[8];
  float mx = -3.4e38f;
  #pragma unroll
  for (int i = 0; i < 8; ++i) {
    v[i] = *(const float4*)(p + ((tid + i * 256) << 2));
    mx = fmaxf(mx, fmaxf(fmaxf(v[i].x, v[i].y), fmaxf(v[i].z, v[i].w)));
  }
  #pragma unroll
  for (int off = 32; off > 0; off >>= 1)
    mx = fmaxf(mx, __shfl_xor(mx, off));
  if ((tid & 63) == 0) redm[tid >> 6] = mx;
  __syncthreads();
  mx = fmaxf(fmaxf(redm[0], redm[1]), fmaxf(redm[2], redm[3]));

  const float c = 1.44269504088896340736f;
  float s = 0.0f;
  #pragma unroll
  for (int i = 0; i < 8; ++i) {
    v[i].x = exp2f((v[i].x - mx) * c);
    v[i].y = exp2f((v[i].y - mx) * c);
    v[i].z = exp2f((v[i].z - mx) * c);
    v[i].w = exp2f((v[i].w - mx) * c);
    s += v[i].x + v[i].y + v[i].z + v[i].w;
  }
  #pragma unroll
  for (int off = 32; off > 0; off >>= 1)
    s += __shfl_xor(s, off);
  if ((tid & 63) == 0) reds[tid >> 6] = s;
  __syncthreads();
  s = reds[0] + reds[1] + reds[2] + reds[3];
  const float inv = 1.0f / s;
  const size_t rb4 = (size_t)blockIdx.x * (NROW / 4);

  #pragma unroll
  for (int i = 0; i < 8; ++i) {
    float4 w4;
    w4.x = v[i].x * inv; w4.y = v[i].y * inv;
    w4.z = v[i].z * inv; w4.w = v[i].w * inv;
    *(float4*)(p + ((tid + i * 256) << 2)) = w4;
    if constexpr (EMITH)
      Wh[rb4 + tid + i * 256] =
          make_ushort4(rtn16(w4.x), rtn16(w4.y), rtn16(w4.z), rtn16(w4.w));
  }
}

__global__ void __launch_bounds__(256)
conv_split(const float4* __restrict__ in, const float* __restrict__ wp,
           ushort4* __restrict__ oh, ushort4* __restrict__ ol)
{
  const int i = blockIdx.x * 256 + threadIdx.x;
  const float w = wp[0];
  float a = in[i * 4 + 0].x * w, b = in[i * 4 + 1].x * w;
  float c = in[i * 4 + 2].x * w, d = in[i * 4 + 3].x * w;
  ushort4 h4, l4;
  split2(a, h4.x, l4.x); split2(b, h4.y, l4.y);
  split2(c, h4.z, l4.z); split2(d, h4.w, l4.w);
  oh[i] = h4;
  ol[i] = l4;
}

__global__ void __launch_bounds__(256)
split_mat(const float4* __restrict__ in, ushort4* __restrict__ oh, ushort4* __restrict__ ol)
{
  const int i = blockIdx.x * 256 + threadIdx.x;
  float4 v = in[i];
  ushort4 h4, l4;
  split2(v.x, h4.x, l4.x); split2(v.y, h4.y, l4.y);
  split2(v.z, h4.z, l4.z); split2(v.w, h4.w, l4.w);
  oh[i] = h4;
  ol[i] = l4;
}

template<bool BOTH>
__global__ void __launch_bounds__(256)
transpose_split(const float* __restrict__ in, u16* __restrict__ oh, u16* __restrict__ ol)
{
  __shared__ float t[32][33];
  const int tx = threadIdx.x & 31, ty = threadIdx.x >> 5;
  const int bx = blockIdx.x * 32, by = blockIdx.y * 32;
  #pragma unroll
  for (int i = 0; i < 32; i += 8)
    t[ty + i][tx] = in[(size_t)(by + ty + i) * HID + bx + tx];
  __syncthreads();
  #pragma unroll
  for (int i = 0; i < 32; i += 8) {
    float v = t[tx][ty + i];
    size_t o = (size_t)(bx + ty + i) * HID + by + tx;
    if constexpr (BOTH) {
      u16 h, l; split2(v, h, l);
      oh[o] = h; ol[o] = l;
    } else {
      oh[o] = rtn16(v);
    }
  }
}

extern "C" void kernel_launch(void* const* d_in, const int* in_sizes, int n_in,
                              void* d_out, int out_size, void* d_ws, size_t ws_size,
                              hipStream_t stream)
{
  (void)in_sizes; (void)n_in; (void)out_size;
  const float* speech_embed = (const float*)d_in[0];
  const float* text  = (const float*)d_in[1];
  const float* convw = (const float*)d_in[2];
  const float* Wq = (const float*)d_in[3];
  const float* bq = (const float*)d_in[4];
  const float* Wk = (const float*)d_in[5];
  const float* bk = (const float*)d_in[6];
  const float* Wv = (const float*)d_in[7];
  const float* bv = (const float*)d_in[8];
  const float* Wo = (const float*)d_in[9];
  const float* bo = (const float*)d_in[10];
  float* out = (float*)d_out;

  const size_t NH = (size_t)NROW * HID;
  const size_t NN = (size_t)NROW * NROW;
  const size_t HH = (size_t)HID * HID;

  u16* base = (u16*)d_ws;
  size_t off = 0;
  auto alloc = [&](size_t n) { u16* p = base + off; off += n; return p; };
  u16 *cath = alloc(2 * NH), *catl = alloc(2 * NH);
  u16 *sph = cath,       *spl = catl;
  u16 *txh = cath + NH,  *txl = catl + NH;
  u16 *wqh = alloc(HH), *wql = alloc(HH);
  u16 *wkh = alloc(HH), *wkl = alloc(HH);
  u16 *wvh = alloc(HH);
  u16 *woh = alloc(HH);
  u16 *qh = alloc(2 * NH), *ql = alloc(2 * NH);   // [NCAT][HID]
  u16 *kh = alloc(2 * NH), *kl = alloc(2 * NH);
  u16 *vth = alloc(2 * NH);                       // [HID][NCAT], hi only
  u16 *c1h = qh;                                  // ctx-hi reuses dead q planes
  u16 *c2h = qh + NH;
  const bool pathA = ((off + NN) * sizeof(u16)) <= ws_size;
  u16 *wsh = nullptr;
  if (pathA) wsh = alloc(NN);

  float* tts_out = out;
  float* tts_w   = out + NH;
  float* stt_out = tts_w + NN;
  float* stt_w   = stt_out + NH;

  const dim3 blk(256);
  const dim3 blk5(512);

  conv_split<<<NH / 1024, blk, 0, stream>>>((const float4*)speech_embed, convw,
                                            (ushort4*)sph, (ushort4*)spl);
  split_mat<<<NH / 1024, blk, 0, stream>>>((const float4*)text, (ushort4*)txh, (ushort4*)txl);
  const dim3 tg(32, 32);
  transpose_split<true ><<<tg, blk, 0, stream>>>(Wq, wqh, wql);
  transpose_split<true ><<<tg, blk, 0, stream>>>(Wk, wkh, wkl);
  transpose_split<false><<<tg, blk, 0, stream>>>(Wv, wvh, nullptr);
  transpose_split<false><<<tg, blk, 0, stream>>>(Wo, woh, nullptr);

  const int gProj = (NCAT / 256) * (HID / 128);   // 512  (gemm_big proj)
  const int gVp   = (NCAT / 128) * (HID / 128);   // 1024 (gemm_bt 1-plane)
  const int gS    = (NROW / 256) * (NROW / 256);  // 1024 (logits 256x256)
  const int gPV   = (NROW / 128) * (HID / 128);   // 512

  if (pathA) {
    // q,k projections: 3-plane on the 3-phase big kernel (+bias, split out)
    gemm_big<128, 4, 2, 4, 4, true, 1><<<gProj, blk5, 0, stream>>>(
        cath, catl, HID, wqh, wql, HID, bq, nullptr, qh, ql, HID, HID, 8);
    gemm_big<128, 4, 2, 4, 4, true, 1><<<gProj, blk5, 0, stream>>>(
        cath, catl, HID, wkh, wkl, HID, bk, nullptr, kh, kl, HID, HID, 8);
    // v projection: 1-plane bf16 (feeds only PV; err ~2^-9 * O(1))
    gemm_bt<1, 0, true, 4><<<gVp, blk, 0, stream>>>(
        cath, nullptr, nullptr, HID, wvh, nullptr, HID, bv,
        nullptr, vth, nullptr, NCAT, HID, 8);

    // logits: 3-plane 256x256 (precision-critical, unchanged)
    gemm_big<256, 2, 4, 8, 4, false, 0><<<gS, blk5, 0, stream>>>(
        qh + NH, ql + NH, HID, kh, kl, HID, nullptr, tts_w, nullptr, nullptr, NROW, HID, 32);
    gemm_big<256, 2, 4, 8, 4, false, 0><<<gS, blk5, 0, stream>>>(
        qh, ql, HID, kh + NH, kl + NH, HID, nullptr, stt_w, nullptr, nullptr, NROW, HID, 32);

    // tts: softmax -> PV (1-plane) -> out-proj (1-plane)
    softmax_rows<true><<<NROW, blk, 0, stream>>>(tts_w, (ushort4*)wsh);
    gemm_bt<1, 0, false, 3><<<gPV, blk, 0, stream>>>(
        wsh, nullptr, nullptr, NROW, vth, nullptr, NCAT, nullptr,
        nullptr, c1h, nullptr, HID, NROW, 8);
    gemm_bt<1, 0, true, 0><<<gPV, blk, 0, stream>>>(
        c1h, nullptr, nullptr, HID, woh, nullptr, HID, bo,
        tts_out, nullptr, nullptr, HID, HID, 8);
    // stt
    softmax_rows<true><<<NROW, blk, 0, stream>>>(stt_w, (ushort4*)wsh);
    gemm_bt<1, 0, false, 3><<<gPV, blk, 0, stream>>>(
        wsh, nullptr, nullptr, NROW, vth + NROW, nullptr, NCAT, nullptr,
        nullptr, c2h, nullptr, HID, NROW, 8);
    gemm_bt<1, 0, true, 0><<<gPV, blk, 0, stream>>>(
        c2h, nullptr, nullptr, HID, woh, nullptr, HID, bo,
        stt_out, nullptr, nullptr, HID, HID, 8);
  } else {
    // fallback: no weight-plane buffer; PV splits fp32 weights in-kernel
    gemm_bt<3, 0, true, 1><<<gVp, blk, 0, stream>>>(
        cath, catl, nullptr, HID, wqh, wql, HID, bq, nullptr, qh, ql, HID, HID, 8);
    gemm_bt<3, 0, true, 1><<<gVp, blk, 0, stream>>>(
        cath, catl, nullptr, HID, wkh, wkl, HID, bk, nullptr, kh, kl, HID, HID, 8);
    gemm_bt<1, 0, true, 4><<<gVp, blk, 0, stream>>>(
        cath, nullptr, nullptr, HID, wvh, nullptr, HID, bv,
        nullptr, vth, nullptr, NCAT, HID, 8);
    gemm_big<256, 2, 4, 8, 4, false, 0><<<gS, blk5, 0, stream>>>(
        qh + NH, ql + NH, HID, kh, kl, HID, nullptr, tts_w, nullptr, nullptr, NROW, HID, 32);
    gemm_big<256, 2, 4, 8, 4, false, 0><<<gS, blk5, 0, stream>>>(
        qh, ql, HID, kh + NH, kl + NH, HID, nullptr, stt_w, nullptr, nullptr, NROW, HID, 32);
    softmax_rows<false><<<NROW, blk, 0, stream>>>(tts_w, nullptr);
    softmax_rows<false><<<NROW, blk, 0, stream>>>(stt_w, nullptr);
    gemm_bt<1, 1, false, 3><<<gPV, blk, 0, stream>>>(
        nullptr, nullptr, tts_w, NROW, vth, nullptr, NCAT, nullptr,
        nullptr, c1h, nullptr, HID, NROW, 8);
    gemm_bt<1, 0, true, 0><<<gPV, blk, 0, stream>>>(
        c1h, nullptr, nullptr, HID, woh, nullptr, HID, bo,
        tts_out, nullptr, nullptr, HID, HID, 8);
    gemm_bt<1, 1, false, 3><<<gPV, blk, 0, stream>>>(
        nullptr, nullptr, stt_w, NROW, vth + NROW, nullptr, NCAT, nullptr,
        nullptr, c2h, nullptr, HID, NROW, 8);
    gemm_bt<1, 0, true, 0><<<gPV, blk, 0, stream>>>(
        c2h, nullptr, nullptr, HID, woh, nullptr, HID, bo,
        stt_out, nullptr, nullptr, HID, HID, 8);
  }
}